// Round 3
// baseline (4341.925 us; speedup 1.0000x reference)
//
#include <hip/hip_runtime.h>
#include <hip/hip_bf16.h>

typedef __hip_bfloat16 bf16;

#define B_   8
#define T_   1024
#define C_   768
#define H_   12
#define HD_  64
#define M_   (B_ * T_)   // 8192 rows
#define N3_  (3 * C_)    // 2304 qkv cols

#define TILE 16

// ---------------- QKV projection: fp32 [8192,768] @ [768,2304] + bias -> bf16 Q,K,V [B,H,T,64]
__global__ void qkv_gemm_kernel(const float* __restrict__ x, const float* __restrict__ w,
                                const float* __restrict__ bias,
                                bf16* __restrict__ Q, bf16* __restrict__ K, bf16* __restrict__ V) {
    __shared__ float As[TILE][TILE + 1];
    __shared__ float Bs[TILE][TILE + 1];
    const int tx = threadIdx.x, ty = threadIdx.y;
    const int row = blockIdx.y * TILE + ty;   // [0,8192)
    const int col = blockIdx.x * TILE + tx;   // [0,2304)
    float acc = 0.f;
    for (int k0 = 0; k0 < C_; k0 += TILE) {
        As[ty][tx] = x[(size_t)row * C_ + k0 + tx];
        Bs[ty][tx] = w[(size_t)(k0 + ty) * N3_ + col];
        __syncthreads();
#pragma unroll
        for (int kk = 0; kk < TILE; ++kk) acc += As[ty][kk] * Bs[kk][tx];
        __syncthreads();
    }
    acc += bias[col];
    const int which = col / C_;      // 0=q 1=k 2=v
    const int cc    = col % C_;
    const int h     = cc / HD_;
    const int d     = cc % HD_;
    const int bb    = row / T_;
    const int t     = row % T_;
    const size_t idx = (((size_t)bb * H_ + h) * T_ + t) * HD_ + d;
    const bf16 val = __float2bfloat16(acc);
    if (which == 0)      Q[idx] = val;
    else if (which == 1) K[idx] = val;
    else                 V[idx] = val;
}

// ---------------- Causal attention, one block per (b,h,q) row
__global__ void attn_kernel(const bf16* __restrict__ Q, const bf16* __restrict__ K,
                            const bf16* __restrict__ V, bf16* __restrict__ Y) {
    const int bid = blockIdx.x;          // [0, B*H*T)
    const int qi  = bid % T_;
    const int bh  = bid / T_;            // [0, B*H)
    const bf16* qrow = Q + ((size_t)bh * T_ + qi) * HD_;
    const bf16* Kb   = K + (size_t)bh * T_ * HD_;
    const bf16* Vb   = V + (size_t)bh * T_ * HD_;

    __shared__ float sc[T_];
    __shared__ float qv[HD_];
    __shared__ float red[256];
    const int tid = threadIdx.x;

    if (tid < HD_) qv[tid] = __bfloat162float(qrow[tid]);
    __syncthreads();

    const int nk = qi + 1;               // causal: keys 0..qi inclusive
    // phase 1: scores + local max
    float lmax = -1e30f;
    for (int j = tid; j < nk; j += 256) {
        const bf16* krow = Kb + (size_t)j * HD_;
        float s = 0.f;
#pragma unroll
        for (int d = 0; d < HD_; ++d) s += qv[d] * __bfloat162float(krow[d]);
        s *= 0.125f;                     // 1/sqrt(64)
        sc[j] = s;
        lmax = fmaxf(lmax, s);
    }
    red[tid] = lmax;
    __syncthreads();
    for (int s = 128; s > 0; s >>= 1) {
        if (tid < s) red[tid] = fmaxf(red[tid], red[tid + s]);
        __syncthreads();
    }
    const float m = red[0];
    __syncthreads();

    // phase 2: exp + sum
    float lsum = 0.f;
    for (int j = tid; j < nk; j += 256) {
        const float e = __expf(sc[j] - m);
        sc[j] = e;
        lsum += e;
    }
    red[tid] = lsum;
    __syncthreads();
    for (int s = 128; s > 0; s >>= 1) {
        if (tid < s) red[tid] += red[tid + s];
        __syncthreads();
    }
    const float inv = 1.0f / red[0];
    __syncthreads();

    // phase 3: y[d] = sum_j p_j * V[j][d], 4 partials x 64 dims
    const int d    = tid & 63;
    const int part = tid >> 6;
    float acc = 0.f;
    for (int j = part; j < nk; j += 4)
        acc += sc[j] * __bfloat162float(Vb[(size_t)j * HD_ + d]);
    red[tid] = acc;
    __syncthreads();
    if (part == 0) {
        const float r = red[d] + red[64 + d] + red[128 + d] + red[192 + d];
        const int b_ = bh / H_, h_ = bh % H_;
        Y[(((size_t)b_ * T_ + qi) * C_) + h_ * HD_ + d] = __float2bfloat16(r * inv);
    }
}

// ---------------- Output projection: bf16 Y [8192,768] @ fp32 [768,768] + bias -> fp32 out
__global__ void proj_gemm_kernel(const bf16* __restrict__ y, const float* __restrict__ w,
                                 const float* __restrict__ bias, float* __restrict__ out) {
    __shared__ float As[TILE][TILE + 1];
    __shared__ float Bs[TILE][TILE + 1];
    const int tx = threadIdx.x, ty = threadIdx.y;
    const int row = blockIdx.y * TILE + ty;
    const int col = blockIdx.x * TILE + tx;
    float acc = 0.f;
    for (int k0 = 0; k0 < C_; k0 += TILE) {
        As[ty][tx] = __bfloat162float(y[(size_t)row * C_ + k0 + tx]);
        Bs[ty][tx] = w[(size_t)(k0 + ty) * C_ + col];
        __syncthreads();
#pragma unroll
        for (int kk = 0; kk < TILE; ++kk) acc += As[ty][kk] * Bs[kk][tx];
        __syncthreads();
    }
    acc += bias[col];
    out[(size_t)row * C_ + col] = acc;
}

extern "C" void kernel_launch(void* const* d_in, const int* in_sizes, int n_in,
                              void* d_out, int out_size, void* d_ws, size_t ws_size,
                              hipStream_t stream) {
    const float* x      = (const float*)d_in[0];
    const float* W_attn = (const float*)d_in[1];
    const float* b_attn = (const float*)d_in[2];
    const float* W_proj = (const float*)d_in[3];
    const float* b_proj = (const float*)d_in[4];
    float* out = (float*)d_out;

    // ws layout: Q,K,V,Y each 6291456 bf16 (12.6 MB) -> ~50 MB total
    const size_t per = (size_t)B_ * H_ * T_ * HD_;  // 6291456 elems
    bf16* Q = (bf16*)d_ws;
    bf16* K = Q + per;
    bf16* V = K + per;
    bf16* Y = V + per;

    qkv_gemm_kernel<<<dim3(N3_ / TILE, M_ / TILE), dim3(TILE, TILE), 0, stream>>>(
        x, W_attn, b_attn, Q, K, V);
    attn_kernel<<<dim3(B_ * H_ * T_), dim3(256), 0, stream>>>(Q, K, V, Y);
    proj_gemm_kernel<<<dim3(C_ / TILE, M_ / TILE), dim3(TILE, TILE), 0, stream>>>(
        Y, W_proj, b_proj, out);
}

// Round 4
// 1335.829 us; speedup vs baseline: 3.2504x; 3.2504x over previous
//
#include <hip/hip_runtime.h>
#include <hip/hip_bf16.h>

typedef __hip_bfloat16 bf16;
typedef __attribute__((ext_vector_type(8))) short  bfrag;   // 8 bf16 (4 VGPR) MFMA A/B frag
typedef __attribute__((ext_vector_type(4))) float  facc;    // MFMA C/D frag
typedef __attribute__((ext_vector_type(4))) unsigned int uint4v;

#define B_   8
#define T_   1024
#define C_   768
#define H_   12
#define HD_  64
#define M_   (B_ * T_)   // 8192
#define N3_  (3 * C_)    // 2304

__device__ __forceinline__ void gload_lds16(const bf16* g, bf16* l) {
    __builtin_amdgcn_global_load_lds((const __attribute__((address_space(1))) void*)g,
                                     (__attribute__((address_space(3))) void*)l, 16, 0, 0);
}
__device__ __forceinline__ float bflo(unsigned int u) { return __uint_as_float(u << 16); }
__device__ __forceinline__ float bfhi(unsigned int u) { return __uint_as_float(u & 0xffff0000u); }

// ---------- converts ----------
__global__ void cvt_x_kernel(const float* __restrict__ x, bf16* __restrict__ xb) {
    const size_t i = ((size_t)blockIdx.x * 256 + threadIdx.x) * 4;   // 6291456 total
    const float4 v = *(const float4*)(x + i);
    bf16* o = xb + i;
    o[0] = __float2bfloat16(v.x); o[1] = __float2bfloat16(v.y);
    o[2] = __float2bfloat16(v.z); o[3] = __float2bfloat16(v.w);
}
// w[K][N] fp32 -> wt[N][K] bf16 (tiled transpose)
__global__ void cvt_wT_kernel(const float* __restrict__ w, bf16* __restrict__ wt, int K, int N) {
    __shared__ float tile[32][33];
    const int k0 = blockIdx.y * 32, n0 = blockIdx.x * 32;
    const int tx = threadIdx.x, ty = threadIdx.y;   // 32 x 8
    for (int i = ty; i < 32; i += 8) tile[i][tx] = w[(size_t)(k0 + i) * N + n0 + tx];
    __syncthreads();
    for (int i = ty; i < 32; i += 8)
        wt[(size_t)(n0 + i) * K + k0 + tx] = __float2bfloat16(tile[tx][i]);
}

// ---------- MFMA GEMM-BT core: C[128x128] = A[m0:,:K] * Bt[n0:,:K]^T ----------
// A row-major [M][K] bf16, Bt row-major [N][K] bf16. 256 threads, 4 waves in 2x2.
#define GEMM_BT_BODY(A, Bt, K_, m0, n0, acc)                                            \
    __shared__ bf16 As[128 * 32];                                                       \
    __shared__ bf16 Bs[128 * 32];                                                       \
    const int t = threadIdx.x, w = t >> 6, lane = t & 63;                               \
    const int wm = (w >> 1) * 64, wn = (w & 1) * 64;                                    \
    const int lrow = t >> 2, lk = (t & 3) * 8;                                          \
    const int fr = lane & 15, fq = (lane >> 4) * 8;                                     \
    facc acc[4][4];                                                                     \
    for (int i = 0; i < 4; ++i) for (int j = 0; j < 4; ++j)                             \
        for (int r = 0; r < 4; ++r) acc[i][j][r] = 0.f;                                 \
    for (int k0 = 0; k0 < (K_); k0 += 32) {                                             \
        gload_lds16((A)  + (size_t)(m0 + lrow)      * (K_) + k0 + lk, As + t * 8);      \
        gload_lds16((A)  + (size_t)(m0 + lrow + 64) * (K_) + k0 + lk, As + 2048 + t * 8); \
        gload_lds16((Bt) + (size_t)(n0 + lrow)      * (K_) + k0 + lk, Bs + t * 8);      \
        gload_lds16((Bt) + (size_t)(n0 + lrow + 64) * (K_) + k0 + lk, Bs + 2048 + t * 8); \
        __syncthreads();                                                                \
        bfrag af[4], bfr[4];                                                            \
        for (int i = 0; i < 4; ++i)                                                     \
            af[i] = *(const bfrag*)(As + (wm + i * 16 + fr) * 32 + fq);                 \
        for (int j = 0; j < 4; ++j)                                                     \
            bfr[j] = *(const bfrag*)(Bs + (wn + j * 16 + fr) * 32 + fq);                \
        for (int i = 0; i < 4; ++i)                                                     \
            for (int j = 0; j < 4; ++j)                                                 \
                acc[i][j] = __builtin_amdgcn_mfma_f32_16x16x32_bf16(af[i], bfr[j],      \
                                                                    acc[i][j], 0, 0, 0); \
        __syncthreads();                                                                \
    }

// qkv: A=xb [8192x768], Bt=WaT [2304x768] -> scatter bf16 Q,K,V [B,H,T,64] + bias
__global__ __launch_bounds__(256) void qkv_mfma_kernel(
        const bf16* __restrict__ xb, const bf16* __restrict__ wat,
        const float* __restrict__ bias,
        bf16* __restrict__ Q, bf16* __restrict__ K, bf16* __restrict__ V) {
    const int m0 = blockIdx.y * 128, n0 = blockIdx.x * 128;
    GEMM_BT_BODY(xb, wat, C_, m0, n0, acc)
    for (int i = 0; i < 4; ++i) {
        const int row = m0 + wm + i * 16 + (lane >> 4) * 4;
        for (int j = 0; j < 4; ++j) {
            const int col = n0 + wn + j * 16 + (lane & 15);
            const float bv = bias[col];
            const int which = col / C_;
            const int cc = col - which * C_;
            const int h = cc >> 6, d = cc & 63;
            bf16* dst = (which == 0) ? Q : (which == 1) ? K : V;
            for (int r = 0; r < 4; ++r) {
                const int rr = row + r;
                const int bb = rr >> 10, tt = rr & 1023;
                dst[(((size_t)bb * H_ + h) * T_ + tt) * HD_ + d] =
                    __float2bfloat16(acc[i][j][r] + bv);
            }
        }
    }
}

// proj: A=Y [8192x768] bf16, Bt=WpT [768x768] -> fp32 out + bias
__global__ __launch_bounds__(256) void proj_mfma_kernel(
        const bf16* __restrict__ y, const bf16* __restrict__ wpt,
        const float* __restrict__ bias, float* __restrict__ out) {
    const int m0 = blockIdx.y * 128, n0 = blockIdx.x * 128;
    GEMM_BT_BODY(y, wpt, C_, m0, n0, acc)
    for (int i = 0; i < 4; ++i) {
        const int row = m0 + wm + i * 16 + (lane >> 4) * 4;
        for (int j = 0; j < 4; ++j) {
            const int col = n0 + wn + j * 16 + (lane & 15);
            const float bv = bias[col];
            for (int r = 0; r < 4; ++r)
                out[(size_t)(row + r) * C_ + col] = acc[i][j][r] + bv;
        }
    }
}

// ---------- causal attention, one block per (b,h,q) row, vectorized ----------
__global__ __launch_bounds__(256) void attn_kernel(
        const bf16* __restrict__ Q, const bf16* __restrict__ K,
        const bf16* __restrict__ V, bf16* __restrict__ Y) {
    const int bid = blockIdx.x;
    const int qi  = bid % T_;
    const int bh  = bid / T_;
    const bf16* qrow = Q + ((size_t)bh * T_ + qi) * HD_;
    const bf16* Kb   = K + (size_t)bh * T_ * HD_;
    const bf16* Vb   = V + (size_t)bh * T_ * HD_;

    __shared__ float sc[T_];
    __shared__ float red[256];
    __shared__ float sredv[512];
    const int tid = threadIdx.x;
    const int nk = qi + 1;

    // hoist q row into 64 registers (block-uniform; broadcast loads)
    float qf[64];
    {
        const uint4v* qp = (const uint4v*)qrow;
#pragma unroll
        for (int c = 0; c < 8; ++c) {
            const uint4v u = qp[c];
#pragma unroll
            for (int e = 0; e < 4; ++e) {
                qf[c * 8 + e * 2]     = bflo(u[e]);
                qf[c * 8 + e * 2 + 1] = bfhi(u[e]);
            }
        }
    }

    // phase 1: scores + local max (vector K loads)
    float lmax = -1e30f;
    for (int j = tid; j < nk; j += 256) {
        const uint4v* kr = (const uint4v*)(Kb + (size_t)j * HD_);
        float s = 0.f;
#pragma unroll
        for (int c = 0; c < 8; ++c) {
            const uint4v u = kr[c];
#pragma unroll
            for (int e = 0; e < 4; ++e) {
                s += bflo(u[e]) * qf[c * 8 + e * 2];
                s += bfhi(u[e]) * qf[c * 8 + e * 2 + 1];
            }
        }
        s *= 0.125f;
        sc[j] = s;
        lmax = fmaxf(lmax, s);
    }
    red[tid] = lmax;
    __syncthreads();
    for (int s = 128; s > 0; s >>= 1) {
        if (tid < s) red[tid] = fmaxf(red[tid], red[tid + s]);
        __syncthreads();
    }
    const float m = red[0];
    __syncthreads();

    // phase 2: exp + sum
    float lsum = 0.f;
    for (int j = tid; j < nk; j += 256) {
        const float e = __expf(sc[j] - m);
        sc[j] = e;
        lsum += e;
    }
    red[tid] = lsum;
    __syncthreads();
    for (int s = 128; s > 0; s >>= 1) {
        if (tid < s) red[tid] += red[tid + s];
        __syncthreads();
    }
    const float inv = 1.0f / red[0];
    __syncthreads();

    // phase 3: y[d] = sum_j p_j * V[j][d]; 8 parts x 32 d-pairs
    const int part  = tid >> 5;          // 0..7
    const int dpair = tid & 31;          // d = dpair*2, dpair*2+1
    float a0 = 0.f, a1 = 0.f;
    for (int j = part; j < nk; j += 8) {
        const unsigned int u = *(const unsigned int*)(Vb + (size_t)j * HD_ + dpair * 2);
        const float p = sc[j];
        a0 += p * bflo(u);
        a1 += p * bfhi(u);
    }
    sredv[tid * 2]     = a0;
    sredv[tid * 2 + 1] = a1;
    __syncthreads();
    if (tid < HD_) {
        float r = 0.f;
#pragma unroll
        for (int p = 0; p < 8; ++p)
            r += sredv[((p << 5) + (tid >> 1)) * 2 + (tid & 1)];
        const int b_ = bh / H_, h_ = bh % H_;
        Y[(((size_t)b_ * T_ + qi) * C_) + h_ * HD_ + tid] = __float2bfloat16(r * inv);
    }
}

extern "C" void kernel_launch(void* const* d_in, const int* in_sizes, int n_in,
                              void* d_out, int out_size, void* d_ws, size_t ws_size,
                              hipStream_t stream) {
    const float* x      = (const float*)d_in[0];
    const float* W_attn = (const float*)d_in[1];
    const float* b_attn = (const float*)d_in[2];
    const float* W_proj = (const float*)d_in[3];
    const float* b_proj = (const float*)d_in[4];
    float* out = (float*)d_out;

    // ws: Q,K,V (3x12.58MB) | XbY (12.58MB, Xb reused as Y) | WaT 3.54MB | WpT 1.18MB
    const size_t per = (size_t)B_ * H_ * T_ * HD_;   // 6291456 bf16
    bf16* Q   = (bf16*)d_ws;
    bf16* K   = Q + per;
    bf16* V   = K + per;
    bf16* XbY = V + per;                 // x-bf16, later attention output Y
    bf16* WaT = XbY + per;
    bf16* WpT = WaT + (size_t)N3_ * C_;

    cvt_x_kernel<<<dim3((M_ * C_) / (256 * 4)), dim3(256), 0, stream>>>(x, XbY);
    cvt_wT_kernel<<<dim3(N3_ / 32, C_ / 32), dim3(32, 8), 0, stream>>>(W_attn, WaT, C_, N3_);
    cvt_wT_kernel<<<dim3(C_ / 32, C_ / 32), dim3(32, 8), 0, stream>>>(W_proj, WpT, C_, C_);

    qkv_mfma_kernel<<<dim3(N3_ / 128, M_ / 128), dim3(256), 0, stream>>>(
        XbY, WaT, b_attn, Q, K, V);
    attn_kernel<<<dim3(B_ * H_ * T_), dim3(256), 0, stream>>>(Q, K, V, XbY);
    proj_mfma_kernel<<<dim3(C_ / 128, M_ / 128), dim3(256), 0, stream>>>(
        XbY, WpT, b_proj, out);
}

// Round 5
// 283.365 us; speedup vs baseline: 15.3227x; 4.7142x over previous
//
#include <hip/hip_runtime.h>
#include <hip/hip_bf16.h>

typedef __hip_bfloat16 bf16;
typedef __attribute__((ext_vector_type(8))) short  bfrag;   // 8 bf16 (4 VGPR) MFMA A/B frag
typedef __attribute__((ext_vector_type(4))) float  facc;    // MFMA C/D frag

#define B_   8
#define T_   1024
#define C_   768
#define H_   12
#define HD_  64
#define M_   (B_ * T_)   // 8192
#define N3_  (3 * C_)    // 2304

__device__ __forceinline__ void gload_lds16(const bf16* g, bf16* l) {
    __builtin_amdgcn_global_load_lds((const __attribute__((address_space(1))) void*)g,
                                     (__attribute__((address_space(3))) void*)l, 16, 0, 0);
}

// ---------- converts ----------
__global__ void cvt_x_kernel(const float* __restrict__ x, bf16* __restrict__ xb) {
    const size_t i = ((size_t)blockIdx.x * 256 + threadIdx.x) * 4;
    const float4 v = *(const float4*)(x + i);
    bf16* o = xb + i;
    o[0] = __float2bfloat16(v.x); o[1] = __float2bfloat16(v.y);
    o[2] = __float2bfloat16(v.z); o[3] = __float2bfloat16(v.w);
}
// w[K][N] fp32 -> wt[N][K] bf16 (tiled transpose)
__global__ void cvt_wT_kernel(const float* __restrict__ w, bf16* __restrict__ wt, int K, int N) {
    __shared__ float tile[32][33];
    const int k0 = blockIdx.y * 32, n0 = blockIdx.x * 32;
    const int tx = threadIdx.x, ty = threadIdx.y;   // 32 x 8
    for (int i = ty; i < 32; i += 8) tile[i][tx] = w[(size_t)(k0 + i) * N + n0 + tx];
    __syncthreads();
    for (int i = ty; i < 32; i += 8)
        wt[(size_t)(n0 + i) * K + k0 + tx] = __float2bfloat16(tile[tx][i]);
}

// ---------- MFMA GEMM-BT core (verified R4) ----------
#define GEMM_BT_BODY(A, Bt, K_, m0, n0, acc)                                            \
    __shared__ bf16 As[128 * 32];                                                       \
    __shared__ bf16 Bs[128 * 32];                                                       \
    const int t = threadIdx.x, w = t >> 6, lane = t & 63;                               \
    const int wm = (w >> 1) * 64, wn = (w & 1) * 64;                                    \
    const int lrow = t >> 2, lk = (t & 3) * 8;                                          \
    const int fr = lane & 15, fq = (lane >> 4) * 8;                                     \
    facc acc[4][4];                                                                     \
    for (int i = 0; i < 4; ++i) for (int j = 0; j < 4; ++j)                             \
        for (int r = 0; r < 4; ++r) acc[i][j][r] = 0.f;                                 \
    for (int k0 = 0; k0 < (K_); k0 += 32) {                                             \
        gload_lds16((A)  + (size_t)(m0 + lrow)      * (K_) + k0 + lk, As + t * 8);      \
        gload_lds16((A)  + (size_t)(m0 + lrow + 64) * (K_) + k0 + lk, As + 2048 + t * 8); \
        gload_lds16((Bt) + (size_t)(n0 + lrow)      * (K_) + k0 + lk, Bs + t * 8);      \
        gload_lds16((Bt) + (size_t)(n0 + lrow + 64) * (K_) + k0 + lk, Bs + 2048 + t * 8); \
        __syncthreads();                                                                \
        bfrag af[4], bfr[4];                                                            \
        for (int i = 0; i < 4; ++i)                                                     \
            af[i] = *(const bfrag*)(As + (wm + i * 16 + fr) * 32 + fq);                 \
        for (int j = 0; j < 4; ++j)                                                     \
            bfr[j] = *(const bfrag*)(Bs + (wn + j * 16 + fr) * 32 + fq);                \
        for (int i = 0; i < 4; ++i)                                                     \
            for (int j = 0; j < 4; ++j)                                                 \
                acc[i][j] = __builtin_amdgcn_mfma_f32_16x16x32_bf16(af[i], bfr[j],      \
                                                                    acc[i][j], 0, 0, 0); \
        __syncthreads();                                                                \
    }

// qkv: A=xb [8192x768], Bt=WaT [2304x768] -> Q,K [B,H,T,64] bf16; V transposed Vt [B,H,64,T]
__global__ __launch_bounds__(256) void qkv_mfma_kernel(
        const bf16* __restrict__ xb, const bf16* __restrict__ wat,
        const float* __restrict__ bias,
        bf16* __restrict__ Q, bf16* __restrict__ K, bf16* __restrict__ Vt) {
    const int m0 = blockIdx.y * 128, n0 = blockIdx.x * 128;
    GEMM_BT_BODY(xb, wat, C_, m0, n0, acc)
    for (int i = 0; i < 4; ++i) {
        const int row = m0 + wm + i * 16 + (lane >> 4) * 4;
        for (int j = 0; j < 4; ++j) {
            const int col = n0 + wn + j * 16 + (lane & 15);
            const float bv = bias[col];
            const int which = col / C_;
            const int cc = col - which * C_;
            const int h = cc >> 6, d = cc & 63;
            for (int r = 0; r < 4; ++r) {
                const int rr = row + r;
                const int bb = rr >> 10, tt = rr & 1023;
                const int bh = bb * H_ + h;
                const bf16 val = __float2bfloat16(acc[i][j][r] + bv);
                if (which == 0)      Q[((size_t)bh * T_ + tt) * HD_ + d] = val;
                else if (which == 1) K[((size_t)bh * T_ + tt) * HD_ + d] = val;
                else                 Vt[((size_t)bh * HD_ + d) * T_ + tt] = val;
            }
        }
    }
}

// proj: A=Y [8192x768] bf16, Bt=WpT [768x768] -> fp32 out + bias
__global__ __launch_bounds__(256) void proj_mfma_kernel(
        const bf16* __restrict__ y, const bf16* __restrict__ wpt,
        const float* __restrict__ bias, float* __restrict__ out) {
    const int m0 = blockIdx.y * 128, n0 = blockIdx.x * 128;
    GEMM_BT_BODY(y, wpt, C_, m0, n0, acc)
    for (int i = 0; i < 4; ++i) {
        const int row = m0 + wm + i * 16 + (lane >> 4) * 4;
        for (int j = 0; j < 4; ++j) {
            const int col = n0 + wn + j * 16 + (lane & 15);
            const float bv = bias[col];
            for (int r = 0; r < 4; ++r)
                out[(size_t)(row + r) * C_ + col] = acc[i][j][r] + bv;
        }
    }
}

// ---------- flash attention: Q-tile 64 x K-tile 64, 4 waves (16 Q-rows each) ----------
__global__ __launch_bounds__(256) void flash_attn_kernel(
        const bf16* __restrict__ Q, const bf16* __restrict__ K,
        const bf16* __restrict__ Vt, bf16* __restrict__ Y) {
    const int qt = blockIdx.x;        // 0..15
    const int bh = blockIdx.y;        // 0..95
    const int q0 = qt * 64;
    const int t = threadIdx.x, w = t >> 6, lane = t & 63;
    const int fr = lane & 15, quad = lane >> 4, fq = quad * 8;

    __shared__ bf16 sK[64 * 64];          // [key][dim]
    __shared__ bf16 sVt[64 * 64];         // [dim][key]
    __shared__ bf16 sP[4][16][72];        // wave-private P, row stride 72 (16B aligned)

    // Q A-frags, loaded once from global (wave w rows q0+w*16 .. +15)
    const bf16* qbase = Q + ((size_t)bh * T_ + q0 + w * 16 + fr) * HD_;
    bfrag qa0 = *(const bfrag*)(qbase + fq);
    bfrag qa1 = *(const bfrag*)(qbase + 32 + fq);

    facc o[4];
    for (int nb = 0; nb < 4; ++nb) for (int r = 0; r < 4; ++r) o[nb][r] = 0.f;
    float rowm[4], rowl[4];
    for (int r = 0; r < 4; ++r) { rowm[r] = -1e30f; rowl[r] = 0.f; }

    const bf16* Kbh = K  + (size_t)bh * T_ * HD_;
    const bf16* Vbh = Vt + (size_t)bh * HD_ * T_;

    for (int kt = 0; kt <= qt; ++kt) {
        const int k0 = kt * 64;
        // stage K tile (flat 8KB) and Vt tile (row-strided)
        gload_lds16(Kbh + (size_t)k0 * HD_ + t * 8,        sK + t * 8);
        gload_lds16(Kbh + (size_t)k0 * HD_ + 2048 + t * 8, sK + 2048 + t * 8);
        {
            const int vrow = t >> 3, vc = (t & 7) * 8;
            gload_lds16(Vbh + (size_t)vrow        * T_ + k0 + vc, sVt + t * 8);
            gload_lds16(Vbh + (size_t)(vrow + 32) * T_ + k0 + vc, sVt + 2048 + t * 8);
        }
        __syncthreads();

        // S = Q K^T  (rows m = w*16 + quad*4 + r, cols n = k0 + nb*16 + fr)
        facc s[4];
        for (int nb = 0; nb < 4; ++nb) for (int r = 0; r < 4; ++r) s[nb][r] = 0.f;
        for (int nb = 0; nb < 4; ++nb) {
            bfrag kb0 = *(const bfrag*)(sK + (nb * 16 + fr) * 64 + fq);
            bfrag kb1 = *(const bfrag*)(sK + (nb * 16 + fr) * 64 + 32 + fq);
            s[nb] = __builtin_amdgcn_mfma_f32_16x16x32_bf16(qa0, kb0, s[nb], 0, 0, 0);
            s[nb] = __builtin_amdgcn_mfma_f32_16x16x32_bf16(qa1, kb1, s[nb], 0, 0, 0);
        }

        const int mrow0 = q0 + w * 16 + quad * 4;   // + r
        if (kt == qt) {
            for (int nb = 0; nb < 4; ++nb) {
                const int n_g = k0 + nb * 16 + fr;
                for (int r = 0; r < 4; ++r) {
                    const float v = s[nb][r] * 0.125f;
                    s[nb][r] = (n_g > mrow0 + r) ? -1e30f : v;
                }
            }
        } else {
            for (int nb = 0; nb < 4; ++nb)
                for (int r = 0; r < 4; ++r) s[nb][r] *= 0.125f;
        }

        // online softmax per row r (rows live in 16-lane quad groups)
        float p[4][4];
        for (int r = 0; r < 4; ++r) {
            float mx = fmaxf(fmaxf(s[0][r], s[1][r]), fmaxf(s[2][r], s[3][r]));
            mx = fmaxf(mx, __shfl_xor(mx, 1));
            mx = fmaxf(mx, __shfl_xor(mx, 2));
            mx = fmaxf(mx, __shfl_xor(mx, 4));
            mx = fmaxf(mx, __shfl_xor(mx, 8));
            const float newm = fmaxf(rowm[r], mx);
            const float alpha = __expf(rowm[r] - newm);
            rowm[r] = newm;
            float sum = 0.f;
            for (int nb = 0; nb < 4; ++nb) {
                p[nb][r] = __expf(s[nb][r] - newm);
                sum += p[nb][r];
            }
            sum += __shfl_xor(sum, 1);
            sum += __shfl_xor(sum, 2);
            sum += __shfl_xor(sum, 4);
            sum += __shfl_xor(sum, 8);
            rowl[r] = rowl[r] * alpha + sum;
            for (int nb = 0; nb < 4; ++nb) o[nb][r] *= alpha;
        }

        // pack P (C-layout) -> wave-private LDS (A-layout source); no barrier needed
        for (int nb = 0; nb < 4; ++nb)
            for (int r = 0; r < 4; ++r)
                sP[w][quad * 4 + r][nb * 16 + fr] = __float2bfloat16(p[nb][r]);

        // O += P V  (A = sP rows m, k = key; B = sVt rows d, k = key)
        {
            bfrag pa0 = *(const bfrag*)(&sP[w][fr][fq]);
            bfrag pa1 = *(const bfrag*)(&sP[w][fr][32 + fq]);
            for (int nb = 0; nb < 4; ++nb) {
                bfrag vb0 = *(const bfrag*)(sVt + (nb * 16 + fr) * 64 + fq);
                bfrag vb1 = *(const bfrag*)(sVt + (nb * 16 + fr) * 64 + 32 + fq);
                o[nb] = __builtin_amdgcn_mfma_f32_16x16x32_bf16(pa0, vb0, o[nb], 0, 0, 0);
                o[nb] = __builtin_amdgcn_mfma_f32_16x16x32_bf16(pa1, vb1, o[nb], 0, 0, 0);
            }
        }
        __syncthreads();
    }

    // epilogue: Y[b][t][h*64+d] = o / l
    const int b_ = bh / H_, h_ = bh % H_;
    for (int r = 0; r < 4; ++r) {
        const int tt = q0 + w * 16 + quad * 4 + r;
        const float inv = 1.0f / rowl[r];
        bf16* yrow = Y + ((size_t)b_ * T_ + tt) * C_ + h_ * HD_;
        for (int nb = 0; nb < 4; ++nb)
            yrow[nb * 16 + fr] = __float2bfloat16(o[nb][r] * inv);
    }
}

extern "C" void kernel_launch(void* const* d_in, const int* in_sizes, int n_in,
                              void* d_out, int out_size, void* d_ws, size_t ws_size,
                              hipStream_t stream) {
    const float* x      = (const float*)d_in[0];
    const float* W_attn = (const float*)d_in[1];
    const float* b_attn = (const float*)d_in[2];
    const float* W_proj = (const float*)d_in[3];
    const float* b_proj = (const float*)d_in[4];
    float* out = (float*)d_out;

    const size_t per = (size_t)B_ * H_ * T_ * HD_;   // 6291456 bf16
    bf16* Q   = (bf16*)d_ws;
    bf16* K   = Q + per;
    bf16* Vt  = K + per;                 // transposed V [B,H,64,T]
    bf16* XbY = Vt + per;                // x-bf16, later attention output Y
    bf16* WaT = XbY + per;
    bf16* WpT = WaT + (size_t)N3_ * C_;

    cvt_x_kernel<<<dim3((M_ * C_) / (256 * 4)), dim3(256), 0, stream>>>(x, XbY);
    cvt_wT_kernel<<<dim3(N3_ / 32, C_ / 32), dim3(32, 8), 0, stream>>>(W_attn, WaT, C_, N3_);
    cvt_wT_kernel<<<dim3(C_ / 32, C_ / 32), dim3(32, 8), 0, stream>>>(W_proj, WpT, C_, C_);

    qkv_mfma_kernel<<<dim3(N3_ / 128, M_ / 128), dim3(256), 0, stream>>>(
        XbY, WaT, b_attn, Q, K, Vt);
    flash_attn_kernel<<<dim3(T_ / 64, B_ * H_), dim3(256), 0, stream>>>(Q, K, Vt, XbY);
    proj_mfma_kernel<<<dim3(C_ / 128, M_ / 128), dim3(256), 0, stream>>>(
        XbY, WpT, b_proj, out);
}

// Round 6
// 221.612 us; speedup vs baseline: 19.5924x; 1.2787x over previous
//
#include <hip/hip_runtime.h>
#include <hip/hip_bf16.h>

typedef __hip_bfloat16 bf16;
typedef __attribute__((ext_vector_type(8))) short  bfrag;   // 8 bf16 (4 VGPR) MFMA A/B frag
typedef __attribute__((ext_vector_type(4))) float  facc;    // MFMA C/D frag

#define B_   8
#define T_   1024
#define C_   768
#define H_   12
#define HD_  64
#define M_   (B_ * T_)   // 8192
#define N3_  (3 * C_)    // 2304

__device__ __forceinline__ void gload_lds16(const bf16* g, bf16* l) {
    __builtin_amdgcn_global_load_lds((const __attribute__((address_space(1))) void*)g,
                                     (__attribute__((address_space(3))) void*)l, 16, 0, 0);
}

// ---------- converts ----------
__global__ void cvt_x_kernel(const float* __restrict__ x, bf16* __restrict__ xb) {
    const size_t i = ((size_t)blockIdx.x * 256 + threadIdx.x) * 4;
    const float4 v = *(const float4*)(x + i);
    bf16* o = xb + i;
    o[0] = __float2bfloat16(v.x); o[1] = __float2bfloat16(v.y);
    o[2] = __float2bfloat16(v.z); o[3] = __float2bfloat16(v.w);
}
// w[K][N] fp32 -> wt[N][K] bf16 (tiled transpose)
__global__ void cvt_wT_kernel(const float* __restrict__ w, bf16* __restrict__ wt, int K, int N) {
    __shared__ float tile[32][33];
    const int k0 = blockIdx.y * 32, n0 = blockIdx.x * 32;
    const int tx = threadIdx.x, ty = threadIdx.y;   // 32 x 8
    for (int i = ty; i < 32; i += 8) tile[i][tx] = w[(size_t)(k0 + i) * N + n0 + tx];
    __syncthreads();
    for (int i = ty; i < 32; i += 8)
        wt[(size_t)(n0 + i) * K + k0 + tx] = __float2bfloat16(tile[tx][i]);
}

// ---------- MFMA GEMM-BT core (verified R4) ----------
#define GEMM_BT_BODY(A, Bt, K_, m0, n0, acc)                                            \
    __shared__ bf16 As[128 * 32];                                                       \
    __shared__ bf16 Bs[128 * 32];                                                       \
    const int t = threadIdx.x, w = t >> 6, lane = t & 63;                               \
    const int wm = (w >> 1) * 64, wn = (w & 1) * 64;                                    \
    const int lrow = t >> 2, lk = (t & 3) * 8;                                          \
    const int fr = lane & 15, fq = (lane >> 4) * 8;                                     \
    facc acc[4][4];                                                                     \
    for (int i = 0; i < 4; ++i) for (int j = 0; j < 4; ++j)                             \
        for (int r = 0; r < 4; ++r) acc[i][j][r] = 0.f;                                 \
    for (int k0 = 0; k0 < (K_); k0 += 32) {                                             \
        gload_lds16((A)  + (size_t)(m0 + lrow)      * (K_) + k0 + lk, As + t * 8);      \
        gload_lds16((A)  + (size_t)(m0 + lrow + 64) * (K_) + k0 + lk, As + 2048 + t * 8); \
        gload_lds16((Bt) + (size_t)(n0 + lrow)      * (K_) + k0 + lk, Bs + t * 8);      \
        gload_lds16((Bt) + (size_t)(n0 + lrow + 64) * (K_) + k0 + lk, Bs + 2048 + t * 8); \
        __syncthreads();                                                                \
        bfrag af[4], bfr[4];                                                            \
        for (int i = 0; i < 4; ++i)                                                     \
            af[i] = *(const bfrag*)(As + (wm + i * 16 + fr) * 32 + fq);                 \
        for (int j = 0; j < 4; ++j)                                                     \
            bfr[j] = *(const bfrag*)(Bs + (wn + j * 16 + fr) * 32 + fq);                \
        for (int i = 0; i < 4; ++i)                                                     \
            for (int j = 0; j < 4; ++j)                                                 \
                acc[i][j] = __builtin_amdgcn_mfma_f32_16x16x32_bf16(af[i], bfr[j],      \
                                                                    acc[i][j], 0, 0, 0); \
        __syncthreads();                                                                \
    }

// qkv: A=xb [8192x768], Bt=WaT [2304x768] -> Q,K [B,H,T,64] bf16; V transposed Vt [B,H,64,T]
__global__ __launch_bounds__(256) void qkv_mfma_kernel(
        const bf16* __restrict__ xb, const bf16* __restrict__ wat,
        const float* __restrict__ bias,
        bf16* __restrict__ Q, bf16* __restrict__ K, bf16* __restrict__ Vt) {
    const int m0 = blockIdx.y * 128, n0 = blockIdx.x * 128;
    GEMM_BT_BODY(xb, wat, C_, m0, n0, acc)
    for (int i = 0; i < 4; ++i) {
        const int row = m0 + wm + i * 16 + (lane >> 4) * 4;
        for (int j = 0; j < 4; ++j) {
            const int col = n0 + wn + j * 16 + (lane & 15);
            const float bv = bias[col];
            const int which = col / C_;
            const int cc = col - which * C_;
            const int h = cc >> 6, d = cc & 63;
            for (int r = 0; r < 4; ++r) {
                const int rr = row + r;
                const int bb = rr >> 10, tt = rr & 1023;
                const int bh = bb * H_ + h;
                const bf16 val = __float2bfloat16(acc[i][j][r] + bv);
                if (which == 0)      Q[((size_t)bh * T_ + tt) * HD_ + d] = val;
                else if (which == 1) K[((size_t)bh * T_ + tt) * HD_ + d] = val;
                else                 Vt[((size_t)bh * HD_ + d) * T_ + tt] = val;
            }
        }
    }
}

// proj: A=Y [8192x768] bf16, Bt=WpT [768x768] -> fp32 out + bias
__global__ __launch_bounds__(256) void proj_mfma_kernel(
        const bf16* __restrict__ y, const bf16* __restrict__ wpt,
        const float* __restrict__ bias, float* __restrict__ out) {
    const int m0 = blockIdx.y * 128, n0 = blockIdx.x * 128;
    GEMM_BT_BODY(y, wpt, C_, m0, n0, acc)
    for (int i = 0; i < 4; ++i) {
        const int row = m0 + wm + i * 16 + (lane >> 4) * 4;
        for (int j = 0; j < 4; ++j) {
            const int col = n0 + wn + j * 16 + (lane & 15);
            const float bv = bias[col];
            for (int r = 0; r < 4; ++r)
                out[(size_t)(row + r) * C_ + col] = acc[i][j][r] + bv;
        }
    }
}

// ---------- flash attention ----------
// Grid: 768 blocks, 1-D. Block -> (bh, qpair) with XCD affinity: the 8 blocks of one
// bh share id%8 so they land on one XCD (K/V stay in that XCD's L2: 12 heads = 3 MB).
// Each block does Q-tiles (15-qpair) and (qpair): uniform 17 K-tile iterations.
// LDS K/V tiles are XOR-swizzled (chunk c of row r holds logical chunk c^(r&7)) to
// break the 128B-row bank aliasing while keeping global_load_lds's lane-linear dest.
__global__ __launch_bounds__(256) void flash_attn_kernel(
        const bf16* __restrict__ Q, const bf16* __restrict__ K,
        const bf16* __restrict__ Vt, bf16* __restrict__ Y) {
    const int id   = blockIdx.x;
    const int bh   = (id & 7) * 12 + ((id >> 3) % 12);
    const int qpair = (id >> 3) / 12;                  // 0..7
    const int t = threadIdx.x, w = t >> 6, lane = t & 63;
    const int fr = lane & 15, quad = lane >> 4, fq = quad * 8;

    __shared__ bf16 sK[64 * 64];          // [key][dim], chunk-swizzled
    __shared__ bf16 sVt[64 * 64];         // [dim][key], chunk-swizzled
    __shared__ bf16 sP[4][16][72];        // wave-private P, row stride 72 (16B aligned)

    const bf16* Kbh = K  + (size_t)bh * T_ * HD_;
    const bf16* Vbh = Vt + (size_t)bh * HD_ * T_;
    const int b_ = bh / H_, h_ = bh % H_;

    const int srow = t >> 3;                                // 0..31 (staging row)
    const int sgc  = ((t & 7) ^ (srow & 7)) * 8;            // swizzled source chunk
    const int c0   = (quad ^ (fr & 7)) * 8;                 // swizzled read chunk

    for (int phase = 0; phase < 2; ++phase) {
        const int qt = (phase == 0) ? (15 - qpair) : qpair; // heavy tile first
        const int q0 = qt * 64;

        const bf16* qbase = Q + ((size_t)bh * T_ + q0 + w * 16 + fr) * HD_;
        bfrag qa0 = *(const bfrag*)(qbase + fq);
        bfrag qa1 = *(const bfrag*)(qbase + 32 + fq);

        facc o[4];
        for (int nb = 0; nb < 4; ++nb) for (int r = 0; r < 4; ++r) o[nb][r] = 0.f;
        float rowl[4] = {0.f, 0.f, 0.f, 0.f};
        float wm = -1e30f;                                  // wave-level running max

        for (int kt = 0; kt <= qt; ++kt) {
            const int k0 = kt * 64;
            gload_lds16(Kbh + (size_t)(k0 + srow) * HD_ + sgc,      sK + t * 8);
            gload_lds16(Kbh + (size_t)(k0 + 32 + srow) * HD_ + sgc, sK + 2048 + t * 8);
            gload_lds16(Vbh + (size_t)srow * T_ + k0 + sgc,         sVt + t * 8);
            gload_lds16(Vbh + (size_t)(srow + 32) * T_ + k0 + sgc,  sVt + 2048 + t * 8);
            __syncthreads();

            // S = Q K^T  (rows m = w*16 + quad*4 + r, cols n = k0 + nb*16 + fr)
            facc s[4];
            for (int nb = 0; nb < 4; ++nb) for (int r = 0; r < 4; ++r) s[nb][r] = 0.f;
            for (int nb = 0; nb < 4; ++nb) {
                const bf16* kr = sK + (nb * 16 + fr) * 64;
                bfrag kb0 = *(const bfrag*)(kr + c0);
                bfrag kb1 = *(const bfrag*)(kr + (c0 ^ 32));
                s[nb] = __builtin_amdgcn_mfma_f32_16x16x32_bf16(qa0, kb0, s[nb], 0, 0, 0);
                s[nb] = __builtin_amdgcn_mfma_f32_16x16x32_bf16(qa1, kb1, s[nb], 0, 0, 0);
            }

            const int mrow0 = q0 + w * 16 + quad * 4;   // + r
            if (kt == qt) {
                for (int nb = 0; nb < 4; ++nb) {
                    const int n_g = k0 + nb * 16 + fr;
                    for (int r = 0; r < 4; ++r) {
                        const float v = s[nb][r] * 0.125f;
                        s[nb][r] = (n_g > mrow0 + r) ? -1e30f : v;
                    }
                }
            } else {
                for (int nb = 0; nb < 4; ++nb)
                    for (int r = 0; r < 4; ++r) s[nb][r] *= 0.125f;
            }

            // wave-level online softmax (single running max for the wave's 16 rows)
            float mx = s[0][0];
            for (int nb = 0; nb < 4; ++nb)
                for (int r = 0; r < 4; ++r) mx = fmaxf(mx, s[nb][r]);
            mx = fmaxf(mx, __shfl_xor(mx, 1));
            mx = fmaxf(mx, __shfl_xor(mx, 2));
            mx = fmaxf(mx, __shfl_xor(mx, 4));
            mx = fmaxf(mx, __shfl_xor(mx, 8));
            mx = fmaxf(mx, __shfl_xor(mx, 16));
            mx = fmaxf(mx, __shfl_xor(mx, 32));
            const float newm = fmaxf(wm, mx);
            const float alpha = __expf(wm - newm);
            wm = newm;

            float p[4][4];
            for (int nb = 0; nb < 4; ++nb)
                for (int r = 0; r < 4; ++r) p[nb][r] = __expf(s[nb][r] - newm);
            for (int r = 0; r < 4; ++r)
                rowl[r] = rowl[r] * alpha +
                          (p[0][r] + p[1][r] + p[2][r] + p[3][r]);
            for (int nb = 0; nb < 4; ++nb)
                for (int r = 0; r < 4; ++r) o[nb][r] *= alpha;

            // pack P (C-layout) -> wave-private LDS; same-wave, no barrier needed
            for (int nb = 0; nb < 4; ++nb)
                for (int r = 0; r < 4; ++r)
                    sP[w][quad * 4 + r][nb * 16 + fr] = __float2bfloat16(p[nb][r]);

            // O += P V
            {
                bfrag pa0 = *(const bfrag*)(&sP[w][fr][fq]);
                bfrag pa1 = *(const bfrag*)(&sP[w][fr][32 + fq]);
                for (int nb = 0; nb < 4; ++nb) {
                    const bf16* vr = sVt + (nb * 16 + fr) * 64;
                    bfrag vb0 = *(const bfrag*)(vr + c0);
                    bfrag vb1 = *(const bfrag*)(vr + (c0 ^ 32));
                    o[nb] = __builtin_amdgcn_mfma_f32_16x16x32_bf16(pa0, vb0, o[nb], 0, 0, 0);
                    o[nb] = __builtin_amdgcn_mfma_f32_16x16x32_bf16(pa1, vb1, o[nb], 0, 0, 0);
                }
            }
            __syncthreads();
        }

        // epilogue: reduce rowl across the 16 fr-lanes, then Y = o / l
        for (int r = 0; r < 4; ++r) {
            float l = rowl[r];
            l += __shfl_xor(l, 1);
            l += __shfl_xor(l, 2);
            l += __shfl_xor(l, 4);
            l += __shfl_xor(l, 8);
            const float inv = 1.0f / l;
            const int tt = q0 + w * 16 + quad * 4 + r;
            bf16* yrow = Y + ((size_t)b_ * T_ + tt) * C_ + h_ * HD_;
            for (int nb = 0; nb < 4; ++nb)
                yrow[nb * 16 + fr] = __float2bfloat16(o[nb][r] * inv);
        }
    }
}

extern "C" void kernel_launch(void* const* d_in, const int* in_sizes, int n_in,
                              void* d_out, int out_size, void* d_ws, size_t ws_size,
                              hipStream_t stream) {
    const float* x      = (const float*)d_in[0];
    const float* W_attn = (const float*)d_in[1];
    const float* b_attn = (const float*)d_in[2];
    const float* W_proj = (const float*)d_in[3];
    const float* b_proj = (const float*)d_in[4];
    float* out = (float*)d_out;

    const size_t per = (size_t)B_ * H_ * T_ * HD_;   // 6291456 bf16
    bf16* Q   = (bf16*)d_ws;
    bf16* K   = Q + per;
    bf16* Vt  = K + per;                 // transposed V [B,H,64,T]
    bf16* XbY = Vt + per;                // x-bf16, later attention output Y
    bf16* WaT = XbY + per;
    bf16* WpT = WaT + (size_t)N3_ * C_;

    cvt_x_kernel<<<dim3((M_ * C_) / (256 * 4)), dim3(256), 0, stream>>>(x, XbY);
    cvt_wT_kernel<<<dim3(N3_ / 32, C_ / 32), dim3(32, 8), 0, stream>>>(W_attn, WaT, C_, N3_);
    cvt_wT_kernel<<<dim3(C_ / 32, C_ / 32), dim3(32, 8), 0, stream>>>(W_proj, WpT, C_, C_);

    qkv_mfma_kernel<<<dim3(N3_ / 128, M_ / 128), dim3(256), 0, stream>>>(
        XbY, WaT, b_attn, Q, K, Vt);
    flash_attn_kernel<<<dim3(768), dim3(256), 0, stream>>>(Q, K, Vt, XbY);
    proj_mfma_kernel<<<dim3(C_ / 128, M_ / 128), dim3(256), 0, stream>>>(
        XbY, WpT, b_proj, out);
}

// Round 7
// 213.382 us; speedup vs baseline: 20.3482x; 1.0386x over previous
//
#include <hip/hip_runtime.h>
#include <hip/hip_bf16.h>

typedef __hip_bfloat16 bf16;
typedef __attribute__((ext_vector_type(8))) short  bfrag;   // 8 bf16 (4 VGPR) MFMA A/B frag
typedef __attribute__((ext_vector_type(4))) float  facc;    // MFMA C/D frag

#define B_   8
#define T_   1024
#define C_   768
#define H_   12
#define HD_  64
#define M_   (B_ * T_)   // 8192
#define N3_  (3 * C_)    // 2304

__device__ __forceinline__ void gload_lds16(const bf16* g, bf16* l) {
    __builtin_amdgcn_global_load_lds((const __attribute__((address_space(1))) void*)g,
                                     (__attribute__((address_space(3))) void*)l, 16, 0, 0);
}

// ---------- converts ----------
__global__ void cvt_x_kernel(const float* __restrict__ x, bf16* __restrict__ xb) {
    const size_t i = ((size_t)blockIdx.x * 256 + threadIdx.x) * 4;
    const float4 v = *(const float4*)(x + i);
    bf16* o = xb + i;
    o[0] = __float2bfloat16(v.x); o[1] = __float2bfloat16(v.y);
    o[2] = __float2bfloat16(v.z); o[3] = __float2bfloat16(v.w);
}
// w[K][N] fp32 -> wt[N][K] bf16 (tiled transpose)
__global__ void cvt_wT_kernel(const float* __restrict__ w, bf16* __restrict__ wt, int K, int N) {
    __shared__ float tile[32][33];
    const int k0 = blockIdx.y * 32, n0 = blockIdx.x * 32;
    const int tx = threadIdx.x, ty = threadIdx.y;   // 32 x 8
    for (int i = ty; i < 32; i += 8) tile[i][tx] = w[(size_t)(k0 + i) * N + n0 + tx];
    __syncthreads();
    for (int i = ty; i < 32; i += 8)
        wt[(size_t)(n0 + i) * K + k0 + tx] = __float2bfloat16(tile[tx][i]);
}

// ---------- MFMA GEMM-BT core, BK=64, XOR-swizzled LDS ----------
// LDS rows are 64 elems (128B); physical chunk c (8 elems) of row r holds logical
// chunk c^(r&7). Staging swizzles the *source* address (dest stays lane-linear as
// global_load_lds requires); fragment reads pick pc=(lc)^(fr&7) -> 2 lanes/bank (free).
#define GEMM_BT_BODY(A, Bt, K_, m0, n0, acc)                                            \
    __shared__ bf16 As[128 * 64];                                                       \
    __shared__ bf16 Bs[128 * 64];                                                       \
    const int t = threadIdx.x, w = t >> 6, lane = t & 63;                               \
    const int wm = (w >> 1) * 64, wn = (w & 1) * 64;                                    \
    const int fr = lane & 15, quad = lane >> 4;                                         \
    const int srow8 = lane >> 3;                     /* 0..7 */                         \
    const int schunk = ((lane & 7) ^ srow8) * 8;     /* swizzled source col */          \
    facc acc[4][4];                                                                     \
    for (int i = 0; i < 4; ++i) for (int j = 0; j < 4; ++j)                             \
        for (int r = 0; r < 4; ++r) acc[i][j][r] = 0.f;                                 \
    for (int k0 = 0; k0 < (K_); k0 += 64) {                                             \
        for (int l = 0; l < 4; ++l) {                                                   \
            const int R0 = w * 32 + l * 8;                                              \
            gload_lds16((A)  + (size_t)(m0 + R0 + srow8) * (K_) + k0 + schunk,          \
                        As + R0 * 64 + lane * 8);                                       \
            gload_lds16((Bt) + (size_t)(n0 + R0 + srow8) * (K_) + k0 + schunk,          \
                        Bs + R0 * 64 + lane * 8);                                       \
        }                                                                               \
        __syncthreads();                                                                \
        for (int kk = 0; kk < 2; ++kk) {                                                \
            const int pc = ((kk * 4 + quad) ^ (fr & 7)) * 8;                            \
            bfrag af[4], bfr[4];                                                        \
            for (int i = 0; i < 4; ++i)                                                 \
                af[i] = *(const bfrag*)(As + (wm + i * 16 + fr) * 64 + pc);             \
            for (int j = 0; j < 4; ++j)                                                 \
                bfr[j] = *(const bfrag*)(Bs + (wn + j * 16 + fr) * 64 + pc);            \
            for (int i = 0; i < 4; ++i)                                                 \
                for (int j = 0; j < 4; ++j)                                             \
                    acc[i][j] = __builtin_amdgcn_mfma_f32_16x16x32_bf16(af[i], bfr[j],  \
                                                                        acc[i][j], 0, 0, 0); \
        }                                                                               \
        __syncthreads();                                                                \
    }

// qkv: A=xb [8192x768], Bt=WaT [2304x768] -> Q,K [B,H,T,64] bf16; V transposed Vt [B,H,64,T]
__global__ __launch_bounds__(256) void qkv_mfma_kernel(
        const bf16* __restrict__ xb, const bf16* __restrict__ wat,
        const float* __restrict__ bias,
        bf16* __restrict__ Q, bf16* __restrict__ K, bf16* __restrict__ Vt) {
    const int m0 = blockIdx.y * 128, n0 = blockIdx.x * 128;
    GEMM_BT_BODY(xb, wat, C_, m0, n0, acc)
    for (int i = 0; i < 4; ++i) {
        const int row = m0 + wm + i * 16 + quad * 4;
        for (int j = 0; j < 4; ++j) {
            const int col = n0 + wn + j * 16 + fr;
            const float bv = bias[col];
            const int which = col / C_;
            const int cc = col - which * C_;
            const int h = cc >> 6, d = cc & 63;
            for (int r = 0; r < 4; ++r) {
                const int rr = row + r;
                const int bb = rr >> 10, tt = rr & 1023;
                const int bh = bb * H_ + h;
                const bf16 val = __float2bfloat16(acc[i][j][r] + bv);
                if (which == 0)      Q[((size_t)bh * T_ + tt) * HD_ + d] = val;
                else if (which == 1) K[((size_t)bh * T_ + tt) * HD_ + d] = val;
                else                 Vt[((size_t)bh * HD_ + d) * T_ + tt] = val;
            }
        }
    }
}

// proj: A=Y [8192x768] bf16, Bt=WpT [768x768] -> fp32 out + bias
__global__ __launch_bounds__(256) void proj_mfma_kernel(
        const bf16* __restrict__ y, const bf16* __restrict__ wpt,
        const float* __restrict__ bias, float* __restrict__ out) {
    const int m0 = blockIdx.y * 128, n0 = blockIdx.x * 128;
    GEMM_BT_BODY(y, wpt, C_, m0, n0, acc)
    for (int i = 0; i < 4; ++i) {
        const int row = m0 + wm + i * 16 + quad * 4;
        for (int j = 0; j < 4; ++j) {
            const int col = n0 + wn + j * 16 + fr;
            const float bv = bias[col];
            for (int r = 0; r < 4; ++r)
                out[(size_t)(row + r) * C_ + col] = acc[i][j][r] + bv;
        }
    }
}

// ---------- flash attention (verified R6) ----------
__global__ __launch_bounds__(256) void flash_attn_kernel(
        const bf16* __restrict__ Q, const bf16* __restrict__ K,
        const bf16* __restrict__ Vt, bf16* __restrict__ Y) {
    const int id   = blockIdx.x;
    const int bh   = (id & 7) * 12 + ((id >> 3) % 12);
    const int qpair = (id >> 3) / 12;                  // 0..7
    const int t = threadIdx.x, w = t >> 6, lane = t & 63;
    const int fr = lane & 15, quad = lane >> 4, fq = quad * 8;

    __shared__ bf16 sK[64 * 64];          // [key][dim], chunk-swizzled
    __shared__ bf16 sVt[64 * 64];         // [dim][key], chunk-swizzled
    __shared__ bf16 sP[4][16][72];        // wave-private P, row stride 72 (16B aligned)

    const bf16* Kbh = K  + (size_t)bh * T_ * HD_;
    const bf16* Vbh = Vt + (size_t)bh * HD_ * T_;
    const int b_ = bh / H_, h_ = bh % H_;

    const int srow = t >> 3;                                // 0..31 (staging row)
    const int sgc  = ((t & 7) ^ (srow & 7)) * 8;            // swizzled source chunk
    const int c0   = (quad ^ (fr & 7)) * 8;                 // swizzled read chunk

    for (int phase = 0; phase < 2; ++phase) {
        const int qt = (phase == 0) ? (15 - qpair) : qpair; // heavy tile first
        const int q0 = qt * 64;

        const bf16* qbase = Q + ((size_t)bh * T_ + q0 + w * 16 + fr) * HD_;
        bfrag qa0 = *(const bfrag*)(qbase + fq);
        bfrag qa1 = *(const bfrag*)(qbase + 32 + fq);

        facc o[4];
        for (int nb = 0; nb < 4; ++nb) for (int r = 0; r < 4; ++r) o[nb][r] = 0.f;
        float rowl[4] = {0.f, 0.f, 0.f, 0.f};
        float wm = -1e30f;                                  // wave-level running max

        for (int kt = 0; kt <= qt; ++kt) {
            const int k0 = kt * 64;
            gload_lds16(Kbh + (size_t)(k0 + srow) * HD_ + sgc,      sK + t * 8);
            gload_lds16(Kbh + (size_t)(k0 + 32 + srow) * HD_ + sgc, sK + 2048 + t * 8);
            gload_lds16(Vbh + (size_t)srow * T_ + k0 + sgc,         sVt + t * 8);
            gload_lds16(Vbh + (size_t)(srow + 32) * T_ + k0 + sgc,  sVt + 2048 + t * 8);
            __syncthreads();

            // S = Q K^T
            facc s[4];
            for (int nb = 0; nb < 4; ++nb) for (int r = 0; r < 4; ++r) s[nb][r] = 0.f;
            for (int nb = 0; nb < 4; ++nb) {
                const bf16* kr = sK + (nb * 16 + fr) * 64;
                bfrag kb0 = *(const bfrag*)(kr + c0);
                bfrag kb1 = *(const bfrag*)(kr + (c0 ^ 32));
                s[nb] = __builtin_amdgcn_mfma_f32_16x16x32_bf16(qa0, kb0, s[nb], 0, 0, 0);
                s[nb] = __builtin_amdgcn_mfma_f32_16x16x32_bf16(qa1, kb1, s[nb], 0, 0, 0);
            }

            const int mrow0 = q0 + w * 16 + quad * 4;   // + r
            if (kt == qt) {
                for (int nb = 0; nb < 4; ++nb) {
                    const int n_g = k0 + nb * 16 + fr;
                    for (int r = 0; r < 4; ++r) {
                        const float v = s[nb][r] * 0.125f;
                        s[nb][r] = (n_g > mrow0 + r) ? -1e30f : v;
                    }
                }
            } else {
                for (int nb = 0; nb < 4; ++nb)
                    for (int r = 0; r < 4; ++r) s[nb][r] *= 0.125f;
            }

            // wave-level online softmax
            float mx = s[0][0];
            for (int nb = 0; nb < 4; ++nb)
                for (int r = 0; r < 4; ++r) mx = fmaxf(mx, s[nb][r]);
            mx = fmaxf(mx, __shfl_xor(mx, 1));
            mx = fmaxf(mx, __shfl_xor(mx, 2));
            mx = fmaxf(mx, __shfl_xor(mx, 4));
            mx = fmaxf(mx, __shfl_xor(mx, 8));
            mx = fmaxf(mx, __shfl_xor(mx, 16));
            mx = fmaxf(mx, __shfl_xor(mx, 32));
            const float newm = fmaxf(wm, mx);
            const float alpha = __expf(wm - newm);
            wm = newm;

            float p[4][4];
            for (int nb = 0; nb < 4; ++nb)
                for (int r = 0; r < 4; ++r) p[nb][r] = __expf(s[nb][r] - newm);
            for (int r = 0; r < 4; ++r)
                rowl[r] = rowl[r] * alpha +
                          (p[0][r] + p[1][r] + p[2][r] + p[3][r]);
            for (int nb = 0; nb < 4; ++nb)
                for (int r = 0; r < 4; ++r) o[nb][r] *= alpha;

            // pack P (C-layout) -> wave-private LDS; same-wave, no barrier needed
            for (int nb = 0; nb < 4; ++nb)
                for (int r = 0; r < 4; ++r)
                    sP[w][quad * 4 + r][nb * 16 + fr] = __float2bfloat16(p[nb][r]);

            // O += P V
            {
                bfrag pa0 = *(const bfrag*)(&sP[w][fr][fq]);
                bfrag pa1 = *(const bfrag*)(&sP[w][fr][32 + fq]);
                for (int nb = 0; nb < 4; ++nb) {
                    const bf16* vr = sVt + (nb * 16 + fr) * 64;
                    bfrag vb0 = *(const bfrag*)(vr + c0);
                    bfrag vb1 = *(const bfrag*)(vr + (c0 ^ 32));
                    o[nb] = __builtin_amdgcn_mfma_f32_16x16x32_bf16(pa0, vb0, o[nb], 0, 0, 0);
                    o[nb] = __builtin_amdgcn_mfma_f32_16x16x32_bf16(pa1, vb1, o[nb], 0, 0, 0);
                }
            }
            __syncthreads();
        }

        // epilogue: reduce rowl across the 16 fr-lanes, then Y = o / l
        for (int r = 0; r < 4; ++r) {
            float l = rowl[r];
            l += __shfl_xor(l, 1);
            l += __shfl_xor(l, 2);
            l += __shfl_xor(l, 4);
            l += __shfl_xor(l, 8);
            const float inv = 1.0f / l;
            const int tt = q0 + w * 16 + quad * 4 + r;
            bf16* yrow = Y + ((size_t)b_ * T_ + tt) * C_ + h_ * HD_;
            for (int nb = 0; nb < 4; ++nb)
                yrow[nb * 16 + fr] = __float2bfloat16(o[nb][r] * inv);
        }
    }
}

extern "C" void kernel_launch(void* const* d_in, const int* in_sizes, int n_in,
                              void* d_out, int out_size, void* d_ws, size_t ws_size,
                              hipStream_t stream) {
    const float* x      = (const float*)d_in[0];
    const float* W_attn = (const float*)d_in[1];
    const float* b_attn = (const float*)d_in[2];
    const float* W_proj = (const float*)d_in[3];
    const float* b_proj = (const float*)d_in[4];
    float* out = (float*)d_out;

    const size_t per = (size_t)B_ * H_ * T_ * HD_;   // 6291456 bf16
    bf16* Q   = (bf16*)d_ws;
    bf16* K   = Q + per;
    bf16* Vt  = K + per;                 // transposed V [B,H,64,T]
    bf16* XbY = Vt + per;                // x-bf16, later attention output Y
    bf16* WaT = XbY + per;
    bf16* WpT = WaT + (size_t)N3_ * C_;

    cvt_x_kernel<<<dim3((M_ * C_) / (256 * 4)), dim3(256), 0, stream>>>(x, XbY);
    cvt_wT_kernel<<<dim3(N3_ / 32, C_ / 32), dim3(32, 8), 0, stream>>>(W_attn, WaT, C_, N3_);
    cvt_wT_kernel<<<dim3(C_ / 32, C_ / 32), dim3(32, 8), 0, stream>>>(W_proj, WpT, C_, C_);

    qkv_mfma_kernel<<<dim3(N3_ / 128, M_ / 128), dim3(256), 0, stream>>>(
        XbY, WaT, b_attn, Q, K, Vt);
    flash_attn_kernel<<<dim3(768), dim3(256), 0, stream>>>(Q, K, Vt, XbY);
    proj_mfma_kernel<<<dim3(C_ / 128, M_ / 128), dim3(256), 0, stream>>>(
        XbY, WpT, b_proj, out);
}